// Round 4
// baseline (540.852 us; speedup 1.0000x reference)
//
#include <hip/hip_runtime.h>
#include <cstdint>
#include <cstddef>

// ---- problem constants ----
#define D_MODEL 2048
#define D_INNER 4096
#define D_IN2   8192
#define D_STATE 16
#define D_CONVK 4
#define DT_RANK 128
#define BATCH   2
#define SEQLEN  1024
#define BL      (BATCH*SEQLEN)
#define XDBL_N  (DT_RANK + 2*D_STATE)   // 160
#define XPW_NPAD 256                    // x_proj N padded to 256
#define XPROJ_SPLITS 8

// chunked-scan constants
#define NCHUNK  16
#define LCHUNK  (SEQLEN/NCHUNK)         // 64
#define CHW     (BATCH*D_INNER*D_STATE) // 131072 carry elements

typedef short  s8v  __attribute__((ext_vector_type(8)));   // 8 bf16 in 4 VGPRs
typedef float  f4v  __attribute__((ext_vector_type(4)));

__device__ __forceinline__ float softplus_f(float v) {
    return (v > 20.f) ? v : log1pf(__expf(v));
}
__device__ __forceinline__ float silu_f(float v) {
    return v / (1.f + __expf(-v));
}
__device__ __forceinline__ float bf2f(short s) {
    return __uint_as_float(((uint32_t)(uint16_t)s) << 16);
}
__device__ __forceinline__ uint16_t f2bf(float f) {   // round-to-nearest-even
    uint32_t u = __float_as_uint(f);
    return (uint16_t)((u + 0x7FFFu + ((u >> 16) & 1u)) >> 16);
}
__device__ __forceinline__ uint32_t packbf(float lo, float hi) {
    return ((uint32_t)f2bf(hi) << 16) | (uint32_t)f2bf(lo);
}
// butterfly sum over each aligned quad of lanes via DPP (no LDS pipe)
__device__ __forceinline__ float quad_sum(float p) {
    p += __int_as_float(__builtin_amdgcn_update_dpp(
            0, __float_as_int(p), 0xB1, 0xF, 0xF, true));  // quad_perm [1,0,3,2]
    p += __int_as_float(__builtin_amdgcn_update_dpp(
            0, __float_as_int(p), 0x4E, 0xF, 0xF, true));  // quad_perm [2,3,0,1]
    return p;
}

// async global->LDS, 16B per lane; LDS dest is wave-uniform base + lane*16
#define GLD16(gp, lp)                                                          \
    __builtin_amdgcn_global_load_lds(                                          \
        (const __attribute__((address_space(1))) void*)(gp),                   \
        (__attribute__((address_space(3))) void*)(lp), 16, 0, 0)

// ---- fp32 -> bf16 cast, 8 elems/thread ----
__global__ __launch_bounds__(256)
void cast_bf16_kernel(const float* __restrict__ in, uint32_t* __restrict__ out, int n8)
{
    const int i = blockIdx.x * 256 + threadIdx.x;
    if (i >= n8) return;
    const float4 a = ((const float4*)in)[i * 2];
    const float4 b = ((const float4*)in)[i * 2 + 1];
    uint4 o;
    o.x = packbf(a.x, a.y); o.y = packbf(a.z, a.w);
    o.z = packbf(b.x, b.y); o.w = packbf(b.z, b.w);
    ((uint4*)out)[i] = o;
}

// ---- bf16 MFMA GEMM: C[m,n] = sum_k A[m,k] * W[n,k]  (C = A * W^T) ----
// LDS layout is chunk-slot swizzled to kill ds_read_b128 bank conflicts:
// global 16B chunk c of row r lives at slot (c + (r>>1)) & 3. With this,
// each quarter-wave's b128 read covers all 32 banks at 2 addrs/bank (free).
template<int EPI>
__global__ __launch_bounds__(256)
void gemm_bf16_mfma(const short* __restrict__ A, int lda,
                    const short* __restrict__ W, int ldw,
                    const float* __restrict__ bias,
                    float* __restrict__ C, int ldc,
                    int M, int N, int K, int kchunk)
{
    __shared__ short sA[128 * 32];
    __shared__ short sW[128 * 32];

    const int tid = threadIdx.x;
    const int w   = tid >> 6;
    const int L   = tid & 63;
    const int bm  = blockIdx.y * 128;
    const int bn  = blockIdx.x * 128;
    const int k0  = blockIdx.z * kchunk;
    const int k1  = k0 + kchunk;
    C += (size_t)blockIdx.z * M * ldc;

    const int qa0 = 2 * w, qa1 = 2 * w + 1;
    const int srow = L >> 2;                         // row within 16-row chunk
    // swizzled global chunk for this lane's LDS slot: c = (slot - (row>>1)) & 3
    const int scol = ((((L & 3) - ((L >> 3) & 3)) & 3)) * 8;

    const short* Ag0 = A + (size_t)(bm + qa0 * 16 + srow) * lda + scol;
    const short* Ag1 = A + (size_t)(bm + qa1 * 16 + srow) * lda + scol;
    const short* Wg0 = W + (size_t)(bn + qa0 * 16 + srow) * ldw + scol;
    const short* Wg1 = W + (size_t)(bn + qa1 * 16 + srow) * ldw + scol;

    const int wm = (w >> 1) * 64;
    const int wn = (w & 1) * 64;
    const int cl = L & 15;
    const int qd = L >> 4;
    // reader slot: s = (qd + (row>>1)) & 3 ; row>>1 ≡ cl>>1 (mod 4) since
    // wm, mt*16 are ≡ 0 mod 8 -> uniform across mt/nt.
    const int sslot = ((qd + ((cl >> 1) & 3)) & 3) * 8;

    f4v acc[4][4];
#pragma unroll
    for (int i = 0; i < 4; i++)
#pragma unroll
        for (int j = 0; j < 4; j++) acc[i][j] = (f4v){0.f, 0.f, 0.f, 0.f};

    for (int k = k0; k < k1; k += 32) {
        GLD16(Ag0 + k, &sA[qa0 * 512]);
        GLD16(Ag1 + k, &sA[qa1 * 512]);
        GLD16(Wg0 + k, &sW[qa0 * 512]);
        GLD16(Wg1 + k, &sW[qa1 * 512]);
        __syncthreads();

        s8v a[4], b[4];
#pragma unroll
        for (int mt = 0; mt < 4; mt++)
            a[mt] = *(const s8v*)&sA[(wm + mt * 16 + cl) * 32 + sslot];
#pragma unroll
        for (int nt = 0; nt < 4; nt++)
            b[nt] = *(const s8v*)&sW[(wn + nt * 16 + cl) * 32 + sslot];
#pragma unroll
        for (int mt = 0; mt < 4; mt++)
#pragma unroll
            for (int nt = 0; nt < 4; nt++)
                acc[mt][nt] = __builtin_amdgcn_mfma_f32_16x16x32_bf16(
                    a[mt], b[nt], acc[mt][nt], 0, 0, 0);
        __syncthreads();
    }

#pragma unroll
    for (int mt = 0; mt < 4; mt++) {
        const int row0 = bm + wm + mt * 16 + qd * 4;
#pragma unroll
        for (int nt = 0; nt < 4; nt++) {
            const int col = bn + wn + nt * 16 + cl;
#pragma unroll
            for (int r = 0; r < 4; r++) {
                float v = acc[mt][nt][r];
                if (EPI == 1) v = softplus_f(v + bias[col]);
                C[(size_t)(row0 + r) * ldc + col] = v;
            }
        }
    }
}

// ---- causal depthwise conv1d (K=4) + SiLU; reads x half of xz (fp32), writes bf16 ----
__global__ __launch_bounds__(256)
void conv_silu_kernel(const float* __restrict__ xz,
                      const float* __restrict__ cw,
                      const float* __restrict__ cb,
                      short* __restrict__ x_bf)
{
    const int idx = blockIdx.x * 256 + threadIdx.x;
    const int d  = idx & (D_INNER - 1);
    const int bl = idx >> 12;
    const int l  = bl & (SEQLEN - 1);
    const int b  = bl >> 10;
    const float* xb = xz + (size_t)b * SEQLEN * D_IN2 + d;
    float acc = cb[d];
#pragma unroll
    for (int k = 0; k < D_CONVK; k++) {
        const int ll = l + k - (D_CONVK - 1);
        if (ll >= 0) acc = fmaf(xb[(size_t)ll * D_IN2], cw[d * D_CONVK + k], acc);
    }
    x_bf[idx] = (short)f2bf(silu_f(acc));
}

// ---- reduce x_proj split-K partials -> x_dbl fp32 + bf16 ----
__global__ __launch_bounds__(256)
void reduce_xdbl_kernel(const float* __restrict__ P,
                        float* __restrict__ xf,
                        short* __restrict__ xb)
{
    const int idx = blockIdx.x * 256 + threadIdx.x;
    if (idx >= BL * XDBL_N) return;
    const int m = idx / XDBL_N;
    const int n = idx - m * XDBL_N;
    float s = 0.f;
#pragma unroll
    for (int z = 0; z < XPROJ_SPLITS; z++)
        s += P[(size_t)z * BL * XPW_NPAD + (size_t)m * XPW_NPAD + n];
    xf[idx] = s;
    xb[idx] = (short)f2bf(s);
}

// ================= chunked selective scan =================
// layout: blocks of 64 channels, 4 lanes per channel (one per 4 states).
// h_end/P/h_in: [chunk][b][d][n] fp32 (thread's 4 states = contiguous float4).

// phase 1: local scan with h_in = 0 -> h_end, P = prod(dA). chunks 0..NCHUNK-2.
__global__ __launch_bounds__(256)
void scan_phase1(const short* __restrict__ x_bf, const float* __restrict__ dt,
                 const float* __restrict__ xdbl, const float* __restrict__ A_log,
                 float* __restrict__ h_end, float* __restrict__ Pprod)
{
    const int c   = blockIdx.y;
    const int ch0 = blockIdx.x * 64;
    const int b   = ch0 >> 12;
    const int d0  = ch0 & (D_INNER - 1);
    const int tid = threadIdx.x;
    const int g   = tid >> 2;          // channel in block 0..63
    const int q   = tid & 3;           // state quad
    const int d   = d0 + g;

    const float4 Al = *(const float4*)&A_log[(d << 4) + (q << 2)];
    float An[4] = {-__expf(Al.x), -__expf(Al.y), -__expf(Al.z), -__expf(Al.w)};
    float h[4]  = {0.f, 0.f, 0.f, 0.f};
    float Pp[4] = {1.f, 1.f, 1.f, 1.f};

    __shared__ float s_x [16][68];
    __shared__ float s_dt[16][68];
    __shared__ float s_B [16][20];

    const int lt  = tid >> 4;
    const int ld4 = (tid & 15) * 4;

    for (int sub = 0; sub < LCHUNK / 16; sub++) {
        const int l0 = c * LCHUNK + sub * 16;
        const size_t bl = (size_t)(b * SEQLEN + l0 + lt);
        __syncthreads();
        {
            const short4 sx = *(const short4*)&x_bf[bl * D_INNER + d0 + ld4];
            const float4 dv = *(const float4*)&dt[bl * D_INNER + d0 + ld4];
            *(float4*)&s_x [lt][ld4] =
                make_float4(bf2f(sx.x), bf2f(sx.y), bf2f(sx.z), bf2f(sx.w));
            *(float4*)&s_dt[lt][ld4] = dv;
            if (tid < 64) {
                const int t2 = tid >> 2, k = (tid & 3) * 4;
                const size_t bl2 = (size_t)(b * SEQLEN + l0 + t2);
                *(float4*)&s_B[t2][k] =
                    *(const float4*)&xdbl[bl2 * XDBL_N + DT_RANK + k];
            }
        }
        __syncthreads();
#pragma unroll
        for (int t = 0; t < 16; t++) {
            const float xv  = s_x [t][g];
            const float dtv = s_dt[t][g];
            const float4 Bq = *(const float4*)&s_B[t][q * 4];
            const float Bv[4] = {Bq.x, Bq.y, Bq.z, Bq.w};
            const float dtx = dtv * xv;
#pragma unroll
            for (int j = 0; j < 4; j++) {
                const float dA = __expf(dtv * An[j]);
                h[j]  = fmaf(h[j], dA, dtx * Bv[j]);
                Pp[j] *= dA;
            }
        }
    }
    const size_t i0 = (size_t)c * CHW + (((size_t)(b * D_INNER + d)) << 4) + (q << 2);
    *(float4*)&h_end[i0] = make_float4(h[0], h[1], h[2], h[3]);
    *(float4*)&Pprod[i0] = make_float4(Pp[0], Pp[1], Pp[2], Pp[3]);
}

// phase 2: serial carry over chunks. one thread per (b,d,n).
__global__ __launch_bounds__(256)
void scan_phase2(const float* __restrict__ h_end, const float* __restrict__ P,
                 float* __restrict__ h_in)
{
    const int i = blockIdx.x * 256 + threadIdx.x;   // 0..CHW-1
    float carry = 0.f;
#pragma unroll
    for (int c = 0; c < NCHUNK; c++) {
        h_in[(size_t)c * CHW + i] = carry;
        if (c < NCHUNK - 1)
            carry = fmaf(P[(size_t)c * CHW + i], carry, h_end[(size_t)c * CHW + i]);
    }
}

// phase 3: local scan with true h_in; fuses D-skip + z-gating; y -> bf16.
__global__ __launch_bounds__(256)
void scan_phase3(const short* __restrict__ x_bf, short* __restrict__ y_bf,
                 const float* __restrict__ dt, const float* __restrict__ xdbl,
                 const float* __restrict__ xz, const float* __restrict__ A_log,
                 const float* __restrict__ Dvec, const float* __restrict__ h_in)
{
    const int c   = blockIdx.y;
    const int ch0 = blockIdx.x * 64;
    const int b   = ch0 >> 12;
    const int d0  = ch0 & (D_INNER - 1);
    const int tid = threadIdx.x;
    const int g   = tid >> 2;
    const int q   = tid & 3;
    const int d   = d0 + g;

    const float4 Al = *(const float4*)&A_log[(d << 4) + (q << 2)];
    float An[4] = {-__expf(Al.x), -__expf(Al.y), -__expf(Al.z), -__expf(Al.w)};
    const float Dd = Dvec[d];
    const float4 h4 = *(const float4*)
        &h_in[(size_t)c * CHW + (((size_t)(b * D_INNER + d)) << 4) + (q << 2)];
    float h[4] = {h4.x, h4.y, h4.z, h4.w};

    __shared__ float s_x [16][68];
    __shared__ float s_dt[16][68];
    __shared__ float s_z [16][68];
    __shared__ float s_B [16][20];
    __shared__ float s_C [16][20];

    const int lt  = tid >> 4;
    const int ld4 = (tid & 15) * 4;

    for (int sub = 0; sub < LCHUNK / 16; sub++) {
        const int l0 = c * LCHUNK + sub * 16;
        const size_t bl = (size_t)(b * SEQLEN + l0 + lt);
        __syncthreads();
        {
            const short4 sx = *(const short4*)&x_bf[bl * D_INNER + d0 + ld4];
            const float4 dv = *(const float4*)&dt[bl * D_INNER + d0 + ld4];
            const float4 zv = *(const float4*)&xz[bl * D_IN2 + D_INNER + d0 + ld4];
            *(float4*)&s_x [lt][ld4] =
                make_float4(bf2f(sx.x), bf2f(sx.y), bf2f(sx.z), bf2f(sx.w));
            *(float4*)&s_dt[lt][ld4] = dv;
            *(float4*)&s_z [lt][ld4] = zv;
            if (tid < 128) {
                const int t2 = (tid & 63) >> 2, k = (tid & 3) * 4;
                const size_t bl2 = (size_t)(b * SEQLEN + l0 + t2);
                const int off = (tid < 64) ? 0 : D_STATE;   // wave-uniform
                const float4 v =
                    *(const float4*)&xdbl[bl2 * XDBL_N + DT_RANK + off + k];
                if (tid < 64) *(float4*)&s_B[t2][k] = v;
                else          *(float4*)&s_C[t2][k] = v;
            }
        }
        __syncthreads();
        const size_t orow = (size_t)(b * SEQLEN + l0);
#pragma unroll
        for (int t = 0; t < 16; t++) {
            const float xv  = s_x [t][g];
            const float dtv = s_dt[t][g];
            const float4 Bq = *(const float4*)&s_B[t][q * 4];
            const float4 Cq = *(const float4*)&s_C[t][q * 4];
            const float Bv[4] = {Bq.x, Bq.y, Bq.z, Bq.w};
            const float Cv[4] = {Cq.x, Cq.y, Cq.z, Cq.w};
            const float dtx = dtv * xv;
            float p = 0.f;
#pragma unroll
            for (int j = 0; j < 4; j++) {
                const float dA = __expf(dtv * An[j]);
                h[j] = fmaf(h[j], dA, dtx * Bv[j]);
                p = fmaf(h[j], Cv[j], p);
            }
            p = quad_sum(p);
            if (q == 0) {
                const float yv = fmaf(xv, Dd, p) * silu_f(s_z[t][g]);
                y_bf[(orow + t) * D_INNER + d] = (short)f2bf(yv);
            }
        }
    }
}

extern "C" void kernel_launch(void* const* d_in, const int* in_sizes, int n_in,
                              void* d_out, int out_size, void* d_ws, size_t ws_size,
                              hipStream_t stream)
{
    const float* hidden     = (const float*)d_in[0];
    const float* in_proj_w  = (const float*)d_in[1];
    const float* conv_w     = (const float*)d_in[2];
    const float* conv_b     = (const float*)d_in[3];
    const float* x_proj_w   = (const float*)d_in[4];
    const float* dt_proj_w  = (const float*)d_in[5];
    const float* dt_proj_b  = (const float*)d_in[6];
    const float* A_log      = (const float*)d_in[7];
    const float* Dvec       = (const float*)d_in[8];
    const float* out_proj_w = (const float*)d_in[9];
    float* out = (float*)d_out;

    // ---- workspace layout (stream-ordered aliasing) ----
    const size_t MB = 1ull << 20;
    char* ws = (char*)d_ws;
    float* xz       = (float*)(ws);                 // [0,64)   fp32 [BL,8192]
    short* ipw_bf   = (short*)(ws + 64 * MB);       // [64,96)  in_proj_w bf16 (dead after GEMM1)
    short* x_bf     = (short*)(ws + 64 * MB);       // [64,80)  alias: x_act bf16
    short* y_bf     = (short*)(ws + 80 * MB);       // [80,96)  alias: y bf16 (phase3 writes)
    float* h_end    = (float*)(ws + 80 * MB);       // [80,88)  alias: chunk h_end (dead pre-phase3)
    float* Pbuf     = (float*)(ws + 88 * MB);       // [88,96)  alias: chunk decay products
    float* dt_f32   = (float*)(ws + 96 * MB);       // [96,128) dt fp32 [BL,4096]
    float* P_part   = (float*)(ws + 96 * MB);       // alias: x_proj partials (dead before dt)
    short* opw_bf   = (short*)(ws + 96 * MB);       // alias: out_proj_w bf16 (cast after scan)
    float* h_in     = (float*)(ws + 128 * MB);      // [128,136.4) alias over dead hid_bf/xpw head
    short* hid_bf   = (short*)(ws + 128 * MB);      // [128,136) hidden bf16 (dead after GEMM1)
    short* xpw_bf   = (short*)(ws + 136 * MB);      // [136,138) x_proj_w bf16 (dead after x_proj)
    short* dtw_bf   = (short*)(ws + 138 * MB);      // [138,139) dt_proj_w bf16
    float* xdbl_f   = (float*)(ws + 139 * MB);      // 1.25 MB  [BL,160] fp32
    short* xdbl_bf  = (short*)(ws + 141 * MB);      // 0.625 MB [BL,160] bf16

    const dim3 blk(256);

    // 1) casts for in_proj
    cast_bf16_kernel<<<dim3((BL * D_MODEL / 8 + 255) / 256), blk, 0, stream>>>(
        hidden, (uint32_t*)hid_bf, BL * D_MODEL / 8);
    cast_bf16_kernel<<<dim3((D_IN2 * D_MODEL / 8 + 255) / 256), blk, 0, stream>>>(
        in_proj_w, (uint32_t*)ipw_bf, D_IN2 * D_MODEL / 8);

    // 2) in_proj: xz[BL,8192] = hidden @ in_proj_w^T
    gemm_bf16_mfma<0><<<dim3(D_IN2 / 128, BL / 128, 1), blk, 0, stream>>>(
        hid_bf, D_MODEL, ipw_bf, D_MODEL, nullptr, xz, D_IN2, BL, D_IN2, D_MODEL, D_MODEL);

    // 3) conv + SiLU -> x_bf
    conv_silu_kernel<<<dim3((BL * D_INNER) / 256), blk, 0, stream>>>(
        xz, conv_w, conv_b, x_bf);

    // 4) x_proj (split-K=8, N padded to 256)
    hipMemsetAsync(xpw_bf, 0, (size_t)XPW_NPAD * D_INNER * 2, stream);
    cast_bf16_kernel<<<dim3((XDBL_N * D_INNER / 8 + 255) / 256), blk, 0, stream>>>(
        x_proj_w, (uint32_t*)xpw_bf, XDBL_N * D_INNER / 8);
    gemm_bf16_mfma<0><<<dim3(XPW_NPAD / 128, BL / 128, XPROJ_SPLITS), blk, 0, stream>>>(
        x_bf, D_INNER, xpw_bf, D_INNER, nullptr, P_part, XPW_NPAD,
        BL, XPW_NPAD, D_INNER, D_INNER / XPROJ_SPLITS);
    reduce_xdbl_kernel<<<dim3((BL * XDBL_N + 255) / 256), blk, 0, stream>>>(
        P_part, xdbl_f, xdbl_bf);

    // 5) dt_proj + bias + softplus -> dt_f32
    cast_bf16_kernel<<<dim3((D_INNER * DT_RANK / 8 + 255) / 256), blk, 0, stream>>>(
        dt_proj_w, (uint32_t*)dtw_bf, D_INNER * DT_RANK / 8);
    gemm_bf16_mfma<1><<<dim3(D_INNER / 128, BL / 128, 1), blk, 0, stream>>>(
        xdbl_bf, XDBL_N, dtw_bf, DT_RANK, dt_proj_b, dt_f32, D_INNER,
        BL, D_INNER, DT_RANK, DT_RANK);

    // 6) chunked selective scan
    scan_phase1<<<dim3(BATCH * D_INNER / 64, NCHUNK - 1), blk, 0, stream>>>(
        x_bf, dt_f32, xdbl_f, A_log, h_end, Pbuf);
    scan_phase2<<<dim3(CHW / 256), blk, 0, stream>>>(h_end, Pbuf, h_in);
    scan_phase3<<<dim3(BATCH * D_INNER / 64, NCHUNK), blk, 0, stream>>>(
        x_bf, y_bf, dt_f32, xdbl_f, xz, A_log, Dvec, h_in);

    // 7) out_proj: out = y @ out_proj_w^T
    cast_bf16_kernel<<<dim3((D_MODEL * D_INNER / 8 + 255) / 256), blk, 0, stream>>>(
        out_proj_w, (uint32_t*)opw_bf, D_MODEL * D_INNER / 8);
    gemm_bf16_mfma<0><<<dim3(D_MODEL / 128, BL / 128, 1), blk, 0, stream>>>(
        y_bf, D_INNER, opw_bf, D_INNER, nullptr, out, D_MODEL,
        BL, D_MODEL, D_INNER, D_INNER);
}

// Round 5
// 506.644 us; speedup vs baseline: 1.0675x; 1.0675x over previous
//
#include <hip/hip_runtime.h>
#include <cstdint>
#include <cstddef>

// ---- problem constants ----
#define D_MODEL 2048
#define D_INNER 4096
#define D_IN2   8192
#define D_STATE 16
#define D_CONVK 4
#define DT_RANK 128
#define BATCH   2
#define SEQLEN  1024
#define BL      (BATCH*SEQLEN)
#define XDBL_N  (DT_RANK + 2*D_STATE)   // 160
#define XPW_NPAD 256
#define XPROJ_SPLITS 8

// chunked-scan constants
#define NCHUNK  16
#define LCHUNK  (SEQLEN/NCHUNK)         // 64
#define CHW     (BATCH*D_INNER*D_STATE) // 131072

// fused-cast segment sizes in 2048-elem blocks
#define NB_HID  2048   // 2048*2048*... = 4,194,304 /2048
#define NB_IPW  8192   // 16,777,216 /2048
#define NB_XPW  320    // 655,360 /2048
#define NB_DTW  256    // 524,288 /2048
#define NB_OPW  4096   // 8,388,608 /2048

typedef short  s8v  __attribute__((ext_vector_type(8)));
typedef float  f4v  __attribute__((ext_vector_type(4)));

__device__ __forceinline__ float softplus_f(float v) {
    return (v > 20.f) ? v : log1pf(__expf(v));
}
__device__ __forceinline__ float silu_f(float v) {
    return v / (1.f + __expf(-v));
}
__device__ __forceinline__ float bf2f(short s) {
    return __uint_as_float(((uint32_t)(uint16_t)s) << 16);
}
__device__ __forceinline__ uint16_t f2bf(float f) {
    uint32_t u = __float_as_uint(f);
    return (uint16_t)((u + 0x7FFFu + ((u >> 16) & 1u)) >> 16);
}
__device__ __forceinline__ uint32_t packbf(float lo, float hi) {
    return ((uint32_t)f2bf(hi) << 16) | (uint32_t)f2bf(lo);
}
__device__ __forceinline__ float quad_sum(float p) {
    p += __int_as_float(__builtin_amdgcn_update_dpp(
            0, __float_as_int(p), 0xB1, 0xF, 0xF, true));
    p += __int_as_float(__builtin_amdgcn_update_dpp(
            0, __float_as_int(p), 0x4E, 0xF, 0xF, true));
    return p;
}

#define GLD16(gp, lp)                                                          \
    __builtin_amdgcn_global_load_lds(                                          \
        (const __attribute__((address_space(1))) void*)(gp),                   \
        (__attribute__((address_space(3))) void*)(lp), 16, 0, 0)

// ---- fused fp32->bf16 cast of hidden + all weights, one dispatch ----
__global__ __launch_bounds__(256)
void cast_all_kernel(const float* __restrict__ s0, uint32_t* __restrict__ d0,
                     const float* __restrict__ s1, uint32_t* __restrict__ d1,
                     const float* __restrict__ s2, uint32_t* __restrict__ d2,
                     const float* __restrict__ s3, uint32_t* __restrict__ d3,
                     const float* __restrict__ s4, uint32_t* __restrict__ d4)
{
    int blk = blockIdx.x;
    const float* src; uint32_t* dst; int base;
    if      (blk < NB_HID)                              { src = s0; dst = d0; base = blk; }
    else if (blk < NB_HID + NB_IPW)                     { src = s1; dst = d1; base = blk - NB_HID; }
    else if (blk < NB_HID + NB_IPW + NB_XPW)            { src = s2; dst = d2; base = blk - NB_HID - NB_IPW; }
    else if (blk < NB_HID + NB_IPW + NB_XPW + NB_DTW)   { src = s3; dst = d3; base = blk - NB_HID - NB_IPW - NB_XPW; }
    else                                                { src = s4; dst = d4; base = blk - NB_HID - NB_IPW - NB_XPW - NB_DTW; }
    const int i = base * 256 + threadIdx.x;   // x8-group index
    const float4 a = ((const float4*)src)[i * 2];
    const float4 b = ((const float4*)src)[i * 2 + 1];
    uint4 o;
    o.x = packbf(a.x, a.y); o.y = packbf(a.z, a.w);
    o.z = packbf(b.x, b.y); o.w = packbf(b.z, b.w);
    ((uint4*)dst)[i] = o;
}

// ---- bf16 MFMA GEMM: C[m,n] = sum_k A[m,k] * W[n,k], BK=64 ----
// LDS: row-major 128x64 bf16 per matrix (32 KB total), chunk-slot swizzled:
// 16B chunk c of row r lives at slot (c + r) & 7  -> conflict-free b128 reads.
// EPI: 0 = fp32 store, 1 = softplus(v+bias[n]) fp32, 2 = bf16 store.
template<int EPI>
__global__ __launch_bounds__(256)
void gemm_bf16_mfma(const short* __restrict__ A, int lda,
                    const short* __restrict__ W, int ldw,
                    const float* __restrict__ bias,
                    void* __restrict__ Cv, int ldc,
                    int M, int N, int K, int kchunk)
{
    __shared__ short sA[128 * 64];
    __shared__ short sW[128 * 64];

    const int tid = threadIdx.x;
    const int w   = tid >> 6;
    const int L   = tid & 63;
    const int bm  = blockIdx.y * 128;
    const int bn  = blockIdx.x * 128;
    const int k0  = blockIdx.z * kchunk;

    // staging: wave w stages rows [w*32, w*32+32) of each tile, 4 GLD16 each.
    // lane row-in-group = L>>3, slot = L&7 -> global chunk c = (slot - row)&7.
    const int rsub = L >> 3;
    const int c8   = (((L & 7) - rsub) & 7) * 8;    // elem offset of lane's chunk
    const short* Ag[4]; const short* Wg[4];
#pragma unroll
    for (int j = 0; j < 4; j++) {
        Ag[j] = A + (size_t)(bm + w * 32 + j * 8 + rsub) * lda + c8 + k0;
        Wg[j] = W + (size_t)(bn + w * 32 + j * 8 + rsub) * ldw + c8 + k0;
    }

    const int wm = (w >> 1) * 64;
    const int wn = (w & 1) * 64;
    const int cl = L & 15;
    const int qd = L >> 4;

    f4v acc[4][4];
#pragma unroll
    for (int i = 0; i < 4; i++)
#pragma unroll
        for (int j = 0; j < 4; j++) acc[i][j] = (f4v){0.f, 0.f, 0.f, 0.f};

    for (int k = 0; k < kchunk; k += 64) {
#pragma unroll
        for (int j = 0; j < 4; j++)
            GLD16(Ag[j] + k, &sA[(w * 32 + j * 8) * 64]);
#pragma unroll
        for (int j = 0; j < 4; j++)
            GLD16(Wg[j] + k, &sW[(w * 32 + j * 8) * 64]);
        __syncthreads();
#pragma unroll
        for (int kk = 0; kk < 2; kk++) {
            // reader slot: (chunk + row)&7, row&7 == cl&7 (wm, mt*16 ≡ 0 mod 8)
            const int sl = ((kk * 4 + qd + cl) & 7) * 8;
            s8v a[4], b[4];
#pragma unroll
            for (int mt = 0; mt < 4; mt++)
                a[mt] = *(const s8v*)&sA[(wm + mt * 16 + cl) * 64 + sl];
#pragma unroll
            for (int nt = 0; nt < 4; nt++)
                b[nt] = *(const s8v*)&sW[(wn + nt * 16 + cl) * 64 + sl];
#pragma unroll
            for (int mt = 0; mt < 4; mt++)
#pragma unroll
                for (int nt = 0; nt < 4; nt++)
                    acc[mt][nt] = __builtin_amdgcn_mfma_f32_16x16x32_bf16(
                        a[mt], b[nt], acc[mt][nt], 0, 0, 0);
        }
        __syncthreads();
    }

    float* Cf = (float*)Cv + (size_t)blockIdx.z * M * ldc;   // split-K offset (EPI 0)
    short* Cs = (short*)Cv;
#pragma unroll
    for (int mt = 0; mt < 4; mt++) {
        const int row0 = bm + wm + mt * 16 + qd * 4;
#pragma unroll
        for (int nt = 0; nt < 4; nt++) {
            const int col = bn + wn + nt * 16 + cl;
#pragma unroll
            for (int r = 0; r < 4; r++) {
                float v = acc[mt][nt][r];
                if (EPI == 1) v = softplus_f(v + bias[col]);
                if (EPI == 2) Cs[(size_t)(row0 + r) * ldc + col] = (short)f2bf(v);
                else          Cf[(size_t)(row0 + r) * ldc + col] = v;
            }
        }
    }
}

// ---- causal depthwise conv1d (K=4) + SiLU; reads bf16 xz, writes bf16 x ----
__global__ __launch_bounds__(256)
void conv_silu_kernel(const short* __restrict__ xz_bf,
                      const float* __restrict__ cw,
                      const float* __restrict__ cb,
                      short* __restrict__ x_bf)
{
    const int idx = blockIdx.x * 256 + threadIdx.x;
    const int d  = idx & (D_INNER - 1);
    const int bl = idx >> 12;
    const int l  = bl & (SEQLEN - 1);
    const int b  = bl >> 10;
    const short* xb = xz_bf + (size_t)b * SEQLEN * D_IN2 + d;
    float acc = cb[d];
#pragma unroll
    for (int k = 0; k < D_CONVK; k++) {
        const int ll = l + k - (D_CONVK - 1);
        if (ll >= 0) acc = fmaf(bf2f(xb[(size_t)ll * D_IN2]), cw[d * D_CONVK + k], acc);
    }
    x_bf[idx] = (short)f2bf(silu_f(acc));
}

// ---- reduce x_proj split-K partials -> x_dbl fp32 + bf16 ----
__global__ __launch_bounds__(256)
void reduce_xdbl_kernel(const float* __restrict__ P,
                        float* __restrict__ xf,
                        short* __restrict__ xb)
{
    const int idx = blockIdx.x * 256 + threadIdx.x;
    if (idx >= BL * XDBL_N) return;
    const int m = idx / XDBL_N;
    const int n = idx - m * XDBL_N;
    float s = 0.f;
#pragma unroll
    for (int z = 0; z < XPROJ_SPLITS; z++)
        s += P[(size_t)z * BL * XPW_NPAD + (size_t)m * XPW_NPAD + n];
    xf[idx] = s;
    xb[idx] = (short)f2bf(s);
}

// ================= chunked selective scan =================
__global__ __launch_bounds__(256)
void scan_phase1(const short* __restrict__ x_bf, const float* __restrict__ dt,
                 const float* __restrict__ xdbl, const float* __restrict__ A_log,
                 float* __restrict__ h_end, float* __restrict__ Pprod)
{
    const int c   = blockIdx.y;
    const int ch0 = blockIdx.x * 64;
    const int b   = ch0 >> 12;
    const int d0  = ch0 & (D_INNER - 1);
    const int tid = threadIdx.x;
    const int g   = tid >> 2;
    const int q   = tid & 3;
    const int d   = d0 + g;

    const float4 Al = *(const float4*)&A_log[(d << 4) + (q << 2)];
    float An[4] = {-__expf(Al.x), -__expf(Al.y), -__expf(Al.z), -__expf(Al.w)};
    float h[4]  = {0.f, 0.f, 0.f, 0.f};
    float Pp[4] = {1.f, 1.f, 1.f, 1.f};

    __shared__ float s_x [16][68];
    __shared__ float s_dt[16][68];
    __shared__ float s_B [16][20];

    const int lt  = tid >> 4;
    const int ld4 = (tid & 15) * 4;

    for (int sub = 0; sub < LCHUNK / 16; sub++) {
        const int l0 = c * LCHUNK + sub * 16;
        const size_t bl = (size_t)(b * SEQLEN + l0 + lt);
        __syncthreads();
        {
            const short4 sx = *(const short4*)&x_bf[bl * D_INNER + d0 + ld4];
            const float4 dv = *(const float4*)&dt[bl * D_INNER + d0 + ld4];
            *(float4*)&s_x [lt][ld4] =
                make_float4(bf2f(sx.x), bf2f(sx.y), bf2f(sx.z), bf2f(sx.w));
            *(float4*)&s_dt[lt][ld4] = dv;
            if (tid < 64) {
                const int t2 = tid >> 2, k = (tid & 3) * 4;
                const size_t bl2 = (size_t)(b * SEQLEN + l0 + t2);
                *(float4*)&s_B[t2][k] =
                    *(const float4*)&xdbl[bl2 * XDBL_N + DT_RANK + k];
            }
        }
        __syncthreads();
#pragma unroll
        for (int t = 0; t < 16; t++) {
            const float xv  = s_x [t][g];
            const float dtv = s_dt[t][g];
            const float4 Bq = *(const float4*)&s_B[t][q * 4];
            const float Bv[4] = {Bq.x, Bq.y, Bq.z, Bq.w};
            const float dtx = dtv * xv;
#pragma unroll
            for (int j = 0; j < 4; j++) {
                const float dA = __expf(dtv * An[j]);
                h[j]  = fmaf(h[j], dA, dtx * Bv[j]);
                Pp[j] *= dA;
            }
        }
    }
    const size_t i0 = (size_t)c * CHW + (((size_t)(b * D_INNER + d)) << 4) + (q << 2);
    *(float4*)&h_end[i0] = make_float4(h[0], h[1], h[2], h[3]);
    *(float4*)&Pprod[i0] = make_float4(Pp[0], Pp[1], Pp[2], Pp[3]);
}

__global__ __launch_bounds__(256)
void scan_phase2(const float* __restrict__ h_end, const float* __restrict__ P,
                 float* __restrict__ h_in)
{
    const int i = blockIdx.x * 256 + threadIdx.x;
    float carry = 0.f;
#pragma unroll
    for (int c = 0; c < NCHUNK; c++) {
        h_in[(size_t)c * CHW + i] = carry;
        if (c < NCHUNK - 1)
            carry = fmaf(P[(size_t)c * CHW + i], carry, h_end[(size_t)c * CHW + i]);
    }
}

__global__ __launch_bounds__(256)
void scan_phase3(const short* __restrict__ x_bf, short* __restrict__ y_bf,
                 const float* __restrict__ dt, const float* __restrict__ xdbl,
                 const short* __restrict__ xz_bf, const float* __restrict__ A_log,
                 const float* __restrict__ Dvec, const float* __restrict__ h_in)
{
    const int c   = blockIdx.y;
    const int ch0 = blockIdx.x * 64;
    const int b   = ch0 >> 12;
    const int d0  = ch0 & (D_INNER - 1);
    const int tid = threadIdx.x;
    const int g   = tid >> 2;
    const int q   = tid & 3;
    const int d   = d0 + g;

    const float4 Al = *(const float4*)&A_log[(d << 4) + (q << 2)];
    float An[4] = {-__expf(Al.x), -__expf(Al.y), -__expf(Al.z), -__expf(Al.w)};
    const float Dd = Dvec[d];
    const float4 h4 = *(const float4*)
        &h_in[(size_t)c * CHW + (((size_t)(b * D_INNER + d)) << 4) + (q << 2)];
    float h[4] = {h4.x, h4.y, h4.z, h4.w};

    __shared__ float s_x [16][68];
    __shared__ float s_dt[16][68];
    __shared__ float s_z [16][68];
    __shared__ float s_B [16][20];
    __shared__ float s_C [16][20];

    const int lt  = tid >> 4;
    const int ld4 = (tid & 15) * 4;

    for (int sub = 0; sub < LCHUNK / 16; sub++) {
        const int l0 = c * LCHUNK + sub * 16;
        const size_t bl = (size_t)(b * SEQLEN + l0 + lt);
        __syncthreads();
        {
            const short4 sx = *(const short4*)&x_bf[bl * D_INNER + d0 + ld4];
            const float4 dv = *(const float4*)&dt[bl * D_INNER + d0 + ld4];
            const short4 zv = *(const short4*)&xz_bf[bl * D_IN2 + D_INNER + d0 + ld4];
            *(float4*)&s_x [lt][ld4] =
                make_float4(bf2f(sx.x), bf2f(sx.y), bf2f(sx.z), bf2f(sx.w));
            *(float4*)&s_dt[lt][ld4] = dv;
            *(float4*)&s_z [lt][ld4] =
                make_float4(bf2f(zv.x), bf2f(zv.y), bf2f(zv.z), bf2f(zv.w));
            if (tid < 128) {
                const int t2 = (tid & 63) >> 2, k = (tid & 3) * 4;
                const size_t bl2 = (size_t)(b * SEQLEN + l0 + t2);
                const int off = (tid < 64) ? 0 : D_STATE;
                const float4 v =
                    *(const float4*)&xdbl[bl2 * XDBL_N + DT_RANK + off + k];
                if (tid < 64) *(float4*)&s_B[t2][k] = v;
                else          *(float4*)&s_C[t2][k] = v;
            }
        }
        __syncthreads();
        const size_t orow = (size_t)(b * SEQLEN + l0);
#pragma unroll
        for (int t = 0; t < 16; t++) {
            const float xv  = s_x [t][g];
            const float dtv = s_dt[t][g];
            const float4 Bq = *(const float4*)&s_B[t][q * 4];
            const float4 Cq = *(const float4*)&s_C[t][q * 4];
            const float Bv[4] = {Bq.x, Bq.y, Bq.z, Bq.w};
            const float Cv[4] = {Cq.x, Cq.y, Cq.z, Cq.w};
            const float dtx = dtv * xv;
            float p = 0.f;
#pragma unroll
            for (int j = 0; j < 4; j++) {
                const float dA = __expf(dtv * An[j]);
                h[j] = fmaf(h[j], dA, dtx * Bv[j]);
                p = fmaf(h[j], Cv[j], p);
            }
            p = quad_sum(p);
            if (q == 0) {
                const float yv = fmaf(xv, Dd, p) * silu_f(s_z[t][g]);
                y_bf[(orow + t) * D_INNER + d] = (short)f2bf(yv);
            }
        }
    }
}

extern "C" void kernel_launch(void* const* d_in, const int* in_sizes, int n_in,
                              void* d_out, int out_size, void* d_ws, size_t ws_size,
                              hipStream_t stream)
{
    const float* hidden     = (const float*)d_in[0];
    const float* in_proj_w  = (const float*)d_in[1];
    const float* conv_w     = (const float*)d_in[2];
    const float* conv_b     = (const float*)d_in[3];
    const float* x_proj_w   = (const float*)d_in[4];
    const float* dt_proj_w  = (const float*)d_in[5];
    const float* dt_proj_b  = (const float*)d_in[6];
    const float* A_log      = (const float*)d_in[7];
    const float* Dvec       = (const float*)d_in[8];
    const float* out_proj_w = (const float*)d_in[9];
    float* out = (float*)d_out;

    // ---- workspace layout (stream-ordered aliasing, <= 141.625 MB) ----
    const size_t MB = 1ull << 20;
    char* ws = (char*)d_ws;
    short* xz_bf   = (short*)(ws);                  // [0,32)    bf16 [BL,8192]
    short* x_bf    = (short*)(ws + 32 * MB);        // [32,48)   bf16 [BL,4096]
    short* ipw_bf  = (short*)(ws + 48 * MB);        // [48,80)   dead after in_proj GEMM
    short* y_bf    = (short*)(ws + 48 * MB);        // [48,64)   alias (phase3 writes)
    float* h_end   = (float*)(ws + 64 * MB);        // [64,72)   alias (phase1 writes)
    float* Pbuf    = (float*)(ws + 72 * MB);        // [72,80)   alias (phase1 writes)
    short* hid_bf  = (short*)(ws + 80 * MB);        // [80,88)   dead after in_proj GEMM
    float* h_in    = (float*)(ws + 80 * MB);        // alias (phase2 writes)
    short* opw_bf  = (short*)(ws + 88 * MB);        // [88,104)  live whole launch
    float* P_part  = (float*)(ws + 104 * MB);       // [104,120) dead after reduce
    float* dt_f32  = (float*)(ws + 104 * MB);       // [104,136) alias (dt GEMM writes)
    short* xpw_bf  = (short*)(ws + 136 * MB);       // [136,138) padded [256,4096]
    short* dtw_bf  = (short*)(ws + 138 * MB);       // [138,139)
    float* xdbl_f  = (float*)(ws + 139 * MB);       // 1.25 MB
    short* xdbl_bf = (short*)(ws + 139 * MB + 1310720);  // 0.625 MB

    const dim3 blk(256);

    // 0) zero x_proj_w pad rows, then fused bf16 casts (one dispatch)
    hipMemsetAsync(xpw_bf, 0, (size_t)XPW_NPAD * D_INNER * 2, stream);
    cast_all_kernel<<<dim3(NB_HID + NB_IPW + NB_XPW + NB_DTW + NB_OPW), blk, 0, stream>>>(
        hidden, (uint32_t*)hid_bf, in_proj_w, (uint32_t*)ipw_bf,
        x_proj_w, (uint32_t*)xpw_bf, dt_proj_w, (uint32_t*)dtw_bf,
        out_proj_w, (uint32_t*)opw_bf);

    // 1) in_proj: xz_bf[BL,8192] = hidden @ in_proj_w^T  (bf16 epilogue)
    gemm_bf16_mfma<2><<<dim3(D_IN2 / 128, BL / 128, 1), blk, 0, stream>>>(
        hid_bf, D_MODEL, ipw_bf, D_MODEL, nullptr, xz_bf, D_IN2,
        BL, D_IN2, D_MODEL, D_MODEL);

    // 2) conv + SiLU -> x_bf
    conv_silu_kernel<<<dim3((BL * D_INNER) / 256), blk, 0, stream>>>(
        xz_bf, conv_w, conv_b, x_bf);

    // 3) x_proj (split-K=8, N padded to 256)
    gemm_bf16_mfma<0><<<dim3(XPW_NPAD / 128, BL / 128, XPROJ_SPLITS), blk, 0, stream>>>(
        x_bf, D_INNER, xpw_bf, D_INNER, nullptr, P_part, XPW_NPAD,
        BL, XPW_NPAD, D_INNER, D_INNER / XPROJ_SPLITS);
    reduce_xdbl_kernel<<<dim3((BL * XDBL_N + 255) / 256), blk, 0, stream>>>(
        P_part, xdbl_f, xdbl_bf);

    // 4) dt_proj + bias + softplus -> dt_f32
    gemm_bf16_mfma<1><<<dim3(D_INNER / 128, BL / 128, 1), blk, 0, stream>>>(
        xdbl_bf, XDBL_N, dtw_bf, DT_RANK, dt_proj_b, dt_f32, D_INNER,
        BL, D_INNER, DT_RANK, DT_RANK);

    // 5) chunked selective scan
    scan_phase1<<<dim3(BATCH * D_INNER / 64, NCHUNK - 1), blk, 0, stream>>>(
        x_bf, dt_f32, xdbl_f, A_log, h_end, Pbuf);
    scan_phase2<<<dim3(CHW / 256), blk, 0, stream>>>(h_end, Pbuf, h_in);
    scan_phase3<<<dim3(BATCH * D_INNER / 64, NCHUNK), blk, 0, stream>>>(
        x_bf, y_bf, dt_f32, xdbl_f, xz_bf, A_log, Dvec, h_in);

    // 6) out_proj: out = y @ out_proj_w^T
    gemm_bf16_mfma<0><<<dim3(D_MODEL / 128, BL / 128, 1), blk, 0, stream>>>(
        y_bf, D_INNER, opw_bf, D_INNER, nullptr, out, D_MODEL,
        BL, D_MODEL, D_INNER, D_INNER);
}

// Round 6
// 483.432 us; speedup vs baseline: 1.1188x; 1.0480x over previous
//
#include <hip/hip_runtime.h>
#include <cstdint>
#include <cstddef>

// ---- problem constants ----
#define D_MODEL 2048
#define D_INNER 4096
#define D_IN2   8192
#define D_STATE 16
#define D_CONVK 4
#define DT_RANK 128
#define BATCH   2
#define SEQLEN  1024
#define BL      (BATCH*SEQLEN)
#define XDBL_N  (DT_RANK + 2*D_STATE)   // 160
#define XPW_NPAD 256
#define XPROJ_SPLITS 8

// chunked-scan constants
#define NCHUNK  16
#define LCHUNK  (SEQLEN/NCHUNK)         // 64
#define CHW     (BATCH*D_INNER*D_STATE) // 131072

// fused-cast segment block counts (256 thr/block, 1 uint4 out/thread)
#define NB_HID   2048   // 4,194,304 f32 -> bf16
#define NB_IPW   8192   // 16,777,216
#define NB_XPW   320    // 655,360
#define NB_XPWZ  192    // zero 96 pad rows x 4096 bf16
#define NB_DTW   256    // 524,288
#define NB_OPW   4096   // 8,388,608
#define NB_XDBLZ 320    // zero 2048x160 fp32

typedef short  s8v  __attribute__((ext_vector_type(8)));
typedef float  f4v  __attribute__((ext_vector_type(4)));

__device__ __forceinline__ float softplus_f(float v) {
    return (v > 20.f) ? v : log1pf(__expf(v));
}
__device__ __forceinline__ float silu_f(float v) {
    return v / (1.f + __expf(-v));
}
__device__ __forceinline__ float bf2f(short s) {
    return __uint_as_float(((uint32_t)(uint16_t)s) << 16);
}
__device__ __forceinline__ uint16_t f2bf(float f) {
    uint32_t u = __float_as_uint(f);
    return (uint16_t)((u + 0x7FFFu + ((u >> 16) & 1u)) >> 16);
}
__device__ __forceinline__ uint32_t packbf(float lo, float hi) {
    return ((uint32_t)f2bf(hi) << 16) | (uint32_t)f2bf(lo);
}
__device__ __forceinline__ float quad_sum(float p) {
    p += __int_as_float(__builtin_amdgcn_update_dpp(
            0, __float_as_int(p), 0xB1, 0xF, 0xF, true));
    p += __int_as_float(__builtin_amdgcn_update_dpp(
            0, __float_as_int(p), 0x4E, 0xF, 0xF, true));
    return p;
}

#define GLD16(gp, lp)                                                          \
    __builtin_amdgcn_global_load_lds(                                          \
        (const __attribute__((address_space(1))) void*)(gp),                   \
        (__attribute__((address_space(3))) void*)(lp), 16, 0, 0)

// ---- fused: all fp32->bf16 casts + zero-fills, one dispatch ----
__global__ __launch_bounds__(256)
void cast_all_kernel(const float* __restrict__ s0, uint32_t* __restrict__ d0,
                     const float* __restrict__ s1, uint32_t* __restrict__ d1,
                     const float* __restrict__ s2, uint32_t* __restrict__ d2,
                     const float* __restrict__ s3, uint32_t* __restrict__ d3,
                     const float* __restrict__ s4, uint32_t* __restrict__ d4,
                     uint32_t* __restrict__ z0,    // xpw pad base (uint32 units)
                     uint32_t* __restrict__ z1)    // xdbl_f base
{
    int blk = blockIdx.x;
    const float* src = nullptr; uint32_t* dst; int base; int zero = 0;
    if      (blk < NB_HID) { src = s0; dst = d0; base = blk; }
    else if ((blk -= NB_HID)  < NB_IPW)  { src = s1; dst = d1; base = blk; }
    else if ((blk -= NB_IPW)  < NB_XPW)  { src = s2; dst = d2; base = blk; }
    else if ((blk -= NB_XPW)  < NB_XPWZ) { dst = z0; base = blk; zero = 1; }
    else if ((blk -= NB_XPWZ) < NB_DTW)  { src = s3; dst = d3; base = blk; }
    else if ((blk -= NB_DTW)  < NB_OPW)  { src = s4; dst = d4; base = blk; }
    else                                 { dst = z1; base = blk - NB_OPW; zero = 1; }
    const int i = base * 256 + threadIdx.x;
    if (zero) { ((uint4*)dst)[i] = make_uint4(0u, 0u, 0u, 0u); return; }
    const float4 a = ((const float4*)src)[i * 2];
    const float4 b = ((const float4*)src)[i * 2 + 1];
    uint4 o;
    o.x = packbf(a.x, a.y); o.y = packbf(a.z, a.w);
    o.z = packbf(b.x, b.y); o.w = packbf(b.z, b.w);
    ((uint4*)dst)[i] = o;
}

// ---- bf16 MFMA GEMM: C[m,n] = sum_k A[m,k] * W[n,k], BK=64, swizzled LDS ----
// EPI: 0 = fp32 store, 2 = bf16 store, 3 = fp32 atomicAdd (cols < XDBL_N only).
template<int EPI>
__global__ __launch_bounds__(256)
void gemm_bf16_mfma(const short* __restrict__ A, int lda,
                    const short* __restrict__ W, int ldw,
                    void* __restrict__ Cv, int ldc,
                    int M, int N, int K, int kchunk)
{
    __shared__ short sA[128 * 64];
    __shared__ short sW[128 * 64];

    const int tid = threadIdx.x;
    const int w   = tid >> 6;
    const int L   = tid & 63;
    const int bm  = blockIdx.y * 128;
    const int bn  = blockIdx.x * 128;
    const int k0  = blockIdx.z * kchunk;

    const int rsub = L >> 3;
    const int c8   = (((L & 7) - rsub) & 7) * 8;    // swizzled chunk offset
    const short* Ag[4]; const short* Wg[4];
#pragma unroll
    for (int j = 0; j < 4; j++) {
        Ag[j] = A + (size_t)(bm + w * 32 + j * 8 + rsub) * lda + c8 + k0;
        Wg[j] = W + (size_t)(bn + w * 32 + j * 8 + rsub) * ldw + c8 + k0;
    }

    const int wm = (w >> 1) * 64;
    const int wn = (w & 1) * 64;
    const int cl = L & 15;
    const int qd = L >> 4;

    f4v acc[4][4];
#pragma unroll
    for (int i = 0; i < 4; i++)
#pragma unroll
        for (int j = 0; j < 4; j++) acc[i][j] = (f4v){0.f, 0.f, 0.f, 0.f};

    for (int k = 0; k < kchunk; k += 64) {
#pragma unroll
        for (int j = 0; j < 4; j++)
            GLD16(Ag[j] + k, &sA[(w * 32 + j * 8) * 64]);
#pragma unroll
        for (int j = 0; j < 4; j++)
            GLD16(Wg[j] + k, &sW[(w * 32 + j * 8) * 64]);
        __syncthreads();
#pragma unroll
        for (int kk = 0; kk < 2; kk++) {
            const int sl = ((kk * 4 + qd + cl) & 7) * 8;
            s8v a[4], b[4];
#pragma unroll
            for (int mt = 0; mt < 4; mt++)
                a[mt] = *(const s8v*)&sA[(wm + mt * 16 + cl) * 64 + sl];
#pragma unroll
            for (int nt = 0; nt < 4; nt++)
                b[nt] = *(const s8v*)&sW[(wn + nt * 16 + cl) * 64 + sl];
#pragma unroll
            for (int mt = 0; mt < 4; mt++)
#pragma unroll
                for (int nt = 0; nt < 4; nt++)
                    acc[mt][nt] = __builtin_amdgcn_mfma_f32_16x16x32_bf16(
                        a[mt], b[nt], acc[mt][nt], 0, 0, 0);
        }
        __syncthreads();
    }

    float* Cf = (float*)Cv;
    short* Cs = (short*)Cv;
#pragma unroll
    for (int mt = 0; mt < 4; mt++) {
        const int row0 = bm + wm + mt * 16 + qd * 4;
#pragma unroll
        for (int nt = 0; nt < 4; nt++) {
            const int col = bn + wn + nt * 16 + cl;
            if (EPI == 3 && col >= XDBL_N) continue;
#pragma unroll
            for (int r = 0; r < 4; r++) {
                const float v = acc[mt][nt][r];
                if      (EPI == 2) Cs[(size_t)(row0 + r) * ldc + col] = (short)f2bf(v);
                else if (EPI == 3) atomicAdd(&Cf[(size_t)(row0 + r) * ldc + col], v);
                else               Cf[(size_t)(row0 + r) * ldc + col] = v;
            }
        }
    }
}

// ---- dt_proj: dt = softplus(xdbl_f[:, :128] @ dtw^T + bias), K=128, 1 barrier ----
__global__ __launch_bounds__(256)
void dt_gemm_kernel(const float* __restrict__ Af,   // xdbl_f [BL,160]
                    const short* __restrict__ W,    // dtw_bf [4096,128]
                    const float* __restrict__ bias,
                    float* __restrict__ C)          // dt_f32 [BL,4096]
{
    __shared__ short sA[2 * 128 * 64];   // 32 KB: two 128x64 halves, swizzled
    __shared__ short sW[2 * 128 * 64];   // 32 KB

    const int tid = threadIdx.x;
    const int w   = tid >> 6;
    const int L   = tid & 63;
    const int bm  = blockIdx.y * 128;
    const int bn  = blockIdx.x * 128;

    // A staging: fp32 global -> bf16 swizzled LDS (8 chunks of 16B per thread)
#pragma unroll
    for (int ci = 0; ci < 8; ci++) {
        const int c_lin = tid * 8 + ci;          // 0..2047
        const int r = c_lin >> 4;                // row 0..127
        const int c = c_lin & 15;                // 16B chunk in row (k8)
        const float* src = Af + (size_t)(bm + r) * XDBL_N + c * 8;
        const float4 u = *(const float4*)src;
        const float4 v = *(const float4*)(src + 4);
        const int half = c >> 3, cc = c & 7;
        const int slot = (cc + r) & 7;
        uint4 o;
        o.x = packbf(u.x, u.y); o.y = packbf(u.z, u.w);
        o.z = packbf(v.x, v.y); o.w = packbf(v.z, v.w);
        *(uint4*)&sA[half * 8192 + r * 64 + slot * 8] = o;
    }
    // W staging via GLD16, swizzled
    const int rsub = L >> 3;
    const int c8   = (((L & 7) - rsub) & 7) * 8;
#pragma unroll
    for (int half = 0; half < 2; half++)
#pragma unroll
        for (int j = 0; j < 4; j++)
            GLD16(W + (size_t)(bn + w * 32 + j * 8 + rsub) * DT_RANK + half * 64 + c8,
                  &sW[half * 8192 + (w * 32 + j * 8) * 64]);
    __syncthreads();

    const int wm = (w >> 1) * 64;
    const int wn = (w & 1) * 64;
    const int cl = L & 15;
    const int qd = L >> 4;

    f4v acc[4][4];
#pragma unroll
    for (int i = 0; i < 4; i++)
#pragma unroll
        for (int j = 0; j < 4; j++) acc[i][j] = (f4v){0.f, 0.f, 0.f, 0.f};

#pragma unroll
    for (int ks = 0; ks < 4; ks++) {
        const int half = ks >> 1;
        const int sl = (((ks & 1) * 4 + qd + cl) & 7) * 8;
        s8v a[4], b[4];
#pragma unroll
        for (int mt = 0; mt < 4; mt++)
            a[mt] = *(const s8v*)&sA[half * 8192 + (wm + mt * 16 + cl) * 64 + sl];
#pragma unroll
        for (int nt = 0; nt < 4; nt++)
            b[nt] = *(const s8v*)&sW[half * 8192 + (wn + nt * 16 + cl) * 64 + sl];
#pragma unroll
        for (int mt = 0; mt < 4; mt++)
#pragma unroll
            for (int nt = 0; nt < 4; nt++)
                acc[mt][nt] = __builtin_amdgcn_mfma_f32_16x16x32_bf16(
                    a[mt], b[nt], acc[mt][nt], 0, 0, 0);
    }

#pragma unroll
    for (int mt = 0; mt < 4; mt++) {
        const int row0 = bm + wm + mt * 16 + qd * 4;
#pragma unroll
        for (int nt = 0; nt < 4; nt++) {
            const int col = bn + wn + nt * 16 + cl;
            const float bc = bias[col];
#pragma unroll
            for (int r = 0; r < 4; r++)
                C[(size_t)(row0 + r) * D_INNER + col] = softplus_f(acc[mt][nt][r] + bc);
        }
    }
}

// ---- causal depthwise conv1d (K=4) + SiLU ----
__global__ __launch_bounds__(256)
void conv_silu_kernel(const short* __restrict__ xz_bf,
                      const float* __restrict__ cw,
                      const float* __restrict__ cb,
                      short* __restrict__ x_bf)
{
    const int idx = blockIdx.x * 256 + threadIdx.x;
    const int d  = idx & (D_INNER - 1);
    const int bl = idx >> 12;
    const int l  = bl & (SEQLEN - 1);
    const int b  = bl >> 10;
    const short* xb = xz_bf + (size_t)b * SEQLEN * D_IN2 + d;
    float acc = cb[d];
#pragma unroll
    for (int k = 0; k < D_CONVK; k++) {
        const int ll = l + k - (D_CONVK - 1);
        if (ll >= 0) acc = fmaf(bf2f(xb[(size_t)ll * D_IN2]), cw[d * D_CONVK + k], acc);
    }
    x_bf[idx] = (short)f2bf(silu_f(acc));
}

// ================= chunked selective scan =================
// phase 1: local scan, h_in=0, chunks 0..NCHUNK-2 -> h_end, P.
__global__ __launch_bounds__(256)
void scan_phase1(const short* __restrict__ x_bf, const float* __restrict__ dt,
                 const float* __restrict__ xdbl, const float* __restrict__ A_log,
                 float* __restrict__ h_end, float* __restrict__ Pprod)
{
    const int c   = blockIdx.y;
    const int ch0 = blockIdx.x * 64;
    const int b   = ch0 >> 12;
    const int d0  = ch0 & (D_INNER - 1);
    const int tid = threadIdx.x;
    const int g   = tid >> 2;
    const int q   = tid & 3;
    const int d   = d0 + g;

    const float4 Al = *(const float4*)&A_log[(d << 4) + (q << 2)];
    float An[4] = {-__expf(Al.x), -__expf(Al.y), -__expf(Al.z), -__expf(Al.w)};
    float h[4]  = {0.f, 0.f, 0.f, 0.f};
    float Pp[4] = {1.f, 1.f, 1.f, 1.f};

    __shared__ float s_x [16][68];
    __shared__ float s_dt[16][68];
    __shared__ float s_B [16][20];

    const int lt  = tid >> 4;
    const int ld4 = (tid & 15) * 4;

    for (int sub = 0; sub < LCHUNK / 16; sub++) {
        const int l0 = c * LCHUNK + sub * 16;
        const size_t bl = (size_t)(b * SEQLEN + l0 + lt);
        __syncthreads();
        {
            const short4 sx = *(const short4*)&x_bf[bl * D_INNER + d0 + ld4];
            const float4 dv = *(const float4*)&dt[bl * D_INNER + d0 + ld4];
            *(float4*)&s_x [lt][ld4] =
                make_float4(bf2f(sx.x), bf2f(sx.y), bf2f(sx.z), bf2f(sx.w));
            *(float4*)&s_dt[lt][ld4] = dv;
            if (tid < 64) {
                const int t2 = tid >> 2, k = (tid & 3) * 4;
                const size_t bl2 = (size_t)(b * SEQLEN + l0 + t2);
                *(float4*)&s_B[t2][k] =
                    *(const float4*)&xdbl[bl2 * XDBL_N + DT_RANK + k];
            }
        }
        __syncthreads();
#pragma unroll
        for (int t = 0; t < 16; t++) {
            const float xv  = s_x [t][g];
            const float dtv = s_dt[t][g];
            const float4 Bq = *(const float4*)&s_B[t][q * 4];
            const float Bv[4] = {Bq.x, Bq.y, Bq.z, Bq.w};
            const float dtx = dtv * xv;
#pragma unroll
            for (int j = 0; j < 4; j++) {
                const float dA = __expf(dtv * An[j]);
                h[j]  = fmaf(h[j], dA, dtx * Bv[j]);
                Pp[j] *= dA;
            }
        }
    }
    const size_t i0 = (size_t)c * CHW + (((size_t)(b * D_INNER + d)) << 4) + (q << 2);
    *(float4*)&h_end[i0] = make_float4(h[0], h[1], h[2], h[3]);
    *(float4*)&Pprod[i0] = make_float4(Pp[0], Pp[1], Pp[2], Pp[3]);
}

// phase 3: per-block lookback for h_in, local scan, D-skip + z-gating.
__global__ __launch_bounds__(256)
void scan_phase3(const short* __restrict__ x_bf, short* __restrict__ y_bf,
                 const float* __restrict__ dt, const float* __restrict__ xdbl,
                 const short* __restrict__ xz_bf, const float* __restrict__ A_log,
                 const float* __restrict__ Dvec,
                 const float* __restrict__ h_end, const float* __restrict__ Pbuf)
{
    const int c   = blockIdx.y;
    const int ch0 = blockIdx.x * 64;
    const int b   = ch0 >> 12;
    const int d0  = ch0 & (D_INNER - 1);
    const int tid = threadIdx.x;
    const int g   = tid >> 2;
    const int q   = tid & 3;
    const int d   = d0 + g;

    const float4 Al = *(const float4*)&A_log[(d << 4) + (q << 2)];
    float An[4] = {-__expf(Al.x), -__expf(Al.y), -__expf(Al.z), -__expf(Al.w)};
    const float Dd = Dvec[d];

    // lookback: h_in = scan over predecessor chunks' (h_end, P)
    float h[4] = {0.f, 0.f, 0.f, 0.f};
    const size_t base = (((size_t)(b * D_INNER + d)) << 4) + (q << 2);
    for (int j = 0; j < c; j++) {
        const float4 he = *(const float4*)&h_end[(size_t)j * CHW + base];
        const float4 Pp = *(const float4*)&Pbuf [(size_t)j * CHW + base];
        h[0] = fmaf(Pp.x, h[0], he.x);
        h[1] = fmaf(Pp.y, h[1], he.y);
        h[2] = fmaf(Pp.z, h[2], he.z);
        h[3] = fmaf(Pp.w, h[3], he.w);
    }

    __shared__ float s_x [16][68];
    __shared__ float s_dt[16][68];
    __shared__ float s_z [16][68];
    __shared__ float s_B [16][20];
    __shared__ float s_C [16][20];

    const int lt  = tid >> 4;
    const int ld4 = (tid & 15) * 4;

    for (int sub = 0; sub < LCHUNK / 16; sub++) {
        const int l0 = c * LCHUNK + sub * 16;
        const size_t bl = (size_t)(b * SEQLEN + l0 + lt);
        __syncthreads();
        {
            const short4 sx = *(const short4*)&x_bf[bl * D_INNER + d0 + ld4];
            const float4 dv = *(const float4*)&dt[bl * D_INNER + d0 + ld4];
            const short4 zv = *(const short4*)&xz_bf[bl * D_IN2 + D_INNER + d0 + ld4];
            *(float4*)&s_x [lt][ld4] =
                make_float4(bf2f(sx.x), bf2f(sx.y), bf2f(sx.z), bf2f(sx.w));
            *(float4*)&s_dt[lt][ld4] = dv;
            *(float4*)&s_z [lt][ld4] =
                make_float4(bf2f(zv.x), bf2f(zv.y), bf2f(zv.z), bf2f(zv.w));
            if (tid < 128) {
                const int t2 = (tid & 63) >> 2, k = (tid & 3) * 4;
                const size_t bl2 = (size_t)(b * SEQLEN + l0 + t2);
                const int off = (tid < 64) ? 0 : D_STATE;
                const float4 v =
                    *(const float4*)&xdbl[bl2 * XDBL_N + DT_RANK + off + k];
                if (tid < 64) *(float4*)&s_B[t2][k] = v;
                else          *(float4*)&s_C[t2][k] = v;
            }
        }
        __syncthreads();
        const size_t orow = (size_t)(b * SEQLEN + l0);
#pragma unroll
        for (int t = 0; t < 16; t++) {
            const float xv  = s_x [t][g];
            const float dtv = s_dt[t][g];
            const float4 Bq = *(const float4*)&s_B[t][q * 4];
            const float4 Cq = *(const float4*)&s_C[t][q * 4];
            const float Bv[4] = {Bq.x, Bq.y, Bq.z, Bq.w};
            const float Cv[4] = {Cq.x, Cq.y, Cq.z, Cq.w};
            const float dtx = dtv * xv;
            float p = 0.f;
#pragma unroll
            for (int j = 0; j < 4; j++) {
                const float dA = __expf(dtv * An[j]);
                h[j] = fmaf(h[j], dA, dtx * Bv[j]);
                p = fmaf(h[j], Cv[j], p);
            }
            p = quad_sum(p);
            if (q == 0) {
                const float yv = fmaf(xv, Dd, p) * silu_f(s_z[t][g]);
                y_bf[(orow + t) * D_INNER + d] = (short)f2bf(yv);
            }
        }
    }
}

extern "C" void kernel_launch(void* const* d_in, const int* in_sizes, int n_in,
                              void* d_out, int out_size, void* d_ws, size_t ws_size,
                              hipStream_t stream)
{
    const float* hidden     = (const float*)d_in[0];
    const float* in_proj_w  = (const float*)d_in[1];
    const float* conv_w     = (const float*)d_in[2];
    const float* conv_b     = (const float*)d_in[3];
    const float* x_proj_w   = (const float*)d_in[4];
    const float* dt_proj_w  = (const float*)d_in[5];
    const float* dt_proj_b  = (const float*)d_in[6];
    const float* A_log      = (const float*)d_in[7];
    const float* Dvec       = (const float*)d_in[8];
    const float* out_proj_w = (const float*)d_in[9];
    float* out = (float*)d_out;

    // ---- workspace layout (stream-ordered aliasing, ~140.3 MB) ----
    const size_t MB = 1ull << 20;
    char* ws = (char*)d_ws;
    short* xz_bf   = (short*)(ws);                  // [0,32)   bf16 [BL,8192]
    short* x_bf    = (short*)(ws + 32 * MB);        // [32,48)  bf16 [BL,4096]
    short* ipw_bf  = (short*)(ws + 48 * MB);        // [48,80)  dead after in_proj
    short* y_bf    = (short*)(ws + 48 * MB);        // [48,64)  alias (phase3)
    float* h_end   = (float*)(ws + 64 * MB);        // [64,72)  alias (phase1)
    float* Pbuf    = (float*)(ws + 72 * MB);        // [72,80)  alias (phase1)
    short* hid_bf  = (short*)(ws + 80 * MB);        // [80,88)  dead after in_proj
    short* opw_bf  = (short*)(ws + 88 * MB);        // [88,104)
    float* dt_f32  = (float*)(ws + 104 * MB);       // [104,136)
    short* xpw_bf  = (short*)(ws + 136 * MB);       // [136,138) padded [256,4096]
    short* dtw_bf  = (short*)(ws + 138 * MB);       // [138,139)
    float* xdbl_f  = (float*)(ws + 139 * MB);       // 1.25 MB [BL,160], atomic target

    const dim3 blk(256);

    // 0) fused casts + zero-fills (xpw pad rows, xdbl_f accumulator)
    cast_all_kernel<<<dim3(NB_HID + NB_IPW + NB_XPW + NB_XPWZ + NB_DTW + NB_OPW + NB_XDBLZ),
                     blk, 0, stream>>>(
        hidden, (uint32_t*)hid_bf, in_proj_w, (uint32_t*)ipw_bf,
        x_proj_w, (uint32_t*)xpw_bf, dt_proj_w, (uint32_t*)dtw_bf,
        out_proj_w, (uint32_t*)opw_bf,
        (uint32_t*)(xpw_bf + (size_t)XDBL_N * D_INNER),   // pad start
        (uint32_t*)xdbl_f);

    // 1) in_proj: xz_bf[BL,8192] = hidden @ in_proj_w^T  (bf16 epilogue)
    gemm_bf16_mfma<2><<<dim3(D_IN2 / 128, BL / 128, 1), blk, 0, stream>>>(
        hid_bf, D_MODEL, ipw_bf, D_MODEL, xz_bf, D_IN2,
        BL, D_IN2, D_MODEL, D_MODEL);

    // 2) conv + SiLU -> x_bf
    conv_silu_kernel<<<dim3((BL * D_INNER) / 256), blk, 0, stream>>>(
        xz_bf, conv_w, conv_b, x_bf);

    // 3) x_proj split-K=8: atomicAdd partials straight into xdbl_f[BL,160]
    gemm_bf16_mfma<3><<<dim3(XPW_NPAD / 128, BL / 128, XPROJ_SPLITS), blk, 0, stream>>>(
        x_bf, D_INNER, xpw_bf, D_INNER, xdbl_f, XDBL_N,
        BL, XPW_NPAD, D_INNER, D_INNER / XPROJ_SPLITS);

    // 4) dt_proj + bias + softplus (reads fp32 xdbl_f directly, K=128, 1 barrier)
    dt_gemm_kernel<<<dim3(D_INNER / 128, BL / 128), blk, 0, stream>>>(
        xdbl_f, dtw_bf, dt_proj_b, dt_f32);

    // 5) chunked selective scan (phase2 folded into phase3 lookback)
    scan_phase1<<<dim3(BATCH * D_INNER / 64, NCHUNK - 1), blk, 0, stream>>>(
        x_bf, dt_f32, xdbl_f, A_log, h_end, Pbuf);
    scan_phase3<<<dim3(BATCH * D_INNER / 64, NCHUNK), blk, 0, stream>>>(
        x_bf, y_bf, dt_f32, xdbl_f, xz_bf, A_log, Dvec, h_end, Pbuf);

    // 6) out_proj: out = y @ out_proj_w^T
    gemm_bf16_mfma<0><<<dim3(D_MODEL / 128, BL / 128, 1), blk, 0, stream>>>(
        y_bf, D_INNER, opw_bf, D_INNER, out, D_MODEL,
        BL, D_MODEL, D_INNER, D_INNER);
}

// Round 7
// 448.384 us; speedup vs baseline: 1.2062x; 1.0782x over previous
//
#include <hip/hip_runtime.h>
#include <cstdint>
#include <cstddef>

// ---- problem constants ----
#define D_MODEL 2048
#define D_INNER 4096
#define D_IN2   8192
#define D_STATE 16
#define D_CONVK 4
#define DT_RANK 128
#define BATCH   2
#define SEQLEN  1024
#define BL      (BATCH*SEQLEN)
#define XDBL_N  (DT_RANK + 2*D_STATE)   // 160
#define XPW_NPAD 256
#define XPROJ_SPLITS 8
#define OUT_SPLITS 2

// chunked-scan constants
#define NCHUNK  16
#define LCHUNK  (SEQLEN/NCHUNK)         // 64
#define CHW     (BATCH*D_INNER*D_STATE) // 131072

// fused-cast segment block counts (256 thr/block, 1 uint4 out/thread)
#define NB_HID   2048
#define NB_IPW   8192
#define NB_XPW   320
#define NB_XPWZ  192
#define NB_DTW   256
#define NB_OPW   4096
#define NB_XDBLZ 320

typedef short  s8v  __attribute__((ext_vector_type(8)));
typedef float  f4v  __attribute__((ext_vector_type(4)));

__device__ __forceinline__ float softplus_f(float v) {
    return (v > 20.f) ? v : log1pf(__expf(v));
}
__device__ __forceinline__ float silu_f(float v) {
    return v / (1.f + __expf(-v));
}
__device__ __forceinline__ float bf2f(short s) {
    return __uint_as_float(((uint32_t)(uint16_t)s) << 16);
}
__device__ __forceinline__ uint16_t f2bf(float f) {
    uint32_t u = __float_as_uint(f);
    return (uint16_t)((u + 0x7FFFu + ((u >> 16) & 1u)) >> 16);
}
__device__ __forceinline__ uint32_t packbf(float lo, float hi) {
    return ((uint32_t)f2bf(hi) << 16) | (uint32_t)f2bf(lo);
}
__device__ __forceinline__ float quad_sum(float p) {
    p += __int_as_float(__builtin_amdgcn_update_dpp(
            0, __float_as_int(p), 0xB1, 0xF, 0xF, true));
    p += __int_as_float(__builtin_amdgcn_update_dpp(
            0, __float_as_int(p), 0x4E, 0xF, 0xF, true));
    return p;
}

#define GLD16(gp, lp)                                                          \
    __builtin_amdgcn_global_load_lds(                                          \
        (const __attribute__((address_space(1))) void*)(gp),                   \
        (__attribute__((address_space(3))) void*)(lp), 16, 0, 0)

// ---- fused: all fp32->bf16 casts + zero-fills, one dispatch ----
__global__ __launch_bounds__(256)
void k_cast_all(const float* __restrict__ s0, uint32_t* __restrict__ d0,
                const float* __restrict__ s1, uint32_t* __restrict__ d1,
                const float* __restrict__ s2, uint32_t* __restrict__ d2,
                const float* __restrict__ s3, uint32_t* __restrict__ d3,
                const float* __restrict__ s4, uint32_t* __restrict__ d4,
                uint32_t* __restrict__ z0, uint32_t* __restrict__ z1)
{
    int blk = blockIdx.x;
    const float* src = nullptr; uint32_t* dst; int base; int zero = 0;
    if      (blk < NB_HID) { src = s0; dst = d0; base = blk; }
    else if ((blk -= NB_HID)  < NB_IPW)  { src = s1; dst = d1; base = blk; }
    else if ((blk -= NB_IPW)  < NB_XPW)  { src = s2; dst = d2; base = blk; }
    else if ((blk -= NB_XPW)  < NB_XPWZ) { dst = z0; base = blk; zero = 1; }
    else if ((blk -= NB_XPWZ) < NB_DTW)  { src = s3; dst = d3; base = blk; }
    else if ((blk -= NB_DTW)  < NB_OPW)  { src = s4; dst = d4; base = blk; }
    else                                 { dst = z1; base = blk - NB_OPW; zero = 1; }
    const int i = base * 256 + threadIdx.x;
    if (zero) { ((uint4*)dst)[i] = make_uint4(0u, 0u, 0u, 0u); return; }
    const float4 a = ((const float4*)src)[i * 2];
    const float4 b = ((const float4*)src)[i * 2 + 1];
    uint4 o;
    o.x = packbf(a.x, a.y); o.y = packbf(a.z, a.w);
    o.z = packbf(b.x, b.y); o.w = packbf(b.z, b.w);
    ((uint4*)dst)[i] = o;
}

// ---- bf16 MFMA GEMM body: C[m,n] = sum_k A[m,k]*W[n,k], BK=64, swizzled ----
// EPI: 0 = fp32 store to slice blockIdx.z, 2 = bf16 store, 3 = fp32 atomicAdd.
template<int EPI>
__device__ __forceinline__
void gemm_body(const short* __restrict__ A, int lda,
               const short* __restrict__ W, int ldw,
               void* __restrict__ Cv, int ldc, int M, int kchunk)
{
    __shared__ short sA[128 * 64];
    __shared__ short sW[128 * 64];

    const int tid = threadIdx.x;
    const int w   = tid >> 6;
    const int L   = tid & 63;
    const int bm  = blockIdx.y * 128;
    const int bn  = blockIdx.x * 128;
    const int k0  = blockIdx.z * kchunk;

    const int rsub = L >> 3;
    const int c8   = (((L & 7) - rsub) & 7) * 8;
    const short* Ag[4]; const short* Wg[4];
#pragma unroll
    for (int j = 0; j < 4; j++) {
        Ag[j] = A + (size_t)(bm + w * 32 + j * 8 + rsub) * lda + c8 + k0;
        Wg[j] = W + (size_t)(bn + w * 32 + j * 8 + rsub) * ldw + c8 + k0;
    }

    const int wm = (w >> 1) * 64;
    const int wn = (w & 1) * 64;
    const int cl = L & 15;
    const int qd = L >> 4;

    f4v acc[4][4];
#pragma unroll
    for (int i = 0; i < 4; i++)
#pragma unroll
        for (int j = 0; j < 4; j++) acc[i][j] = (f4v){0.f, 0.f, 0.f, 0.f};

    for (int k = 0; k < kchunk; k += 64) {
#pragma unroll
        for (int j = 0; j < 4; j++)
            GLD16(Ag[j] + k, &sA[(w * 32 + j * 8) * 64]);
#pragma unroll
        for (int j = 0; j < 4; j++)
            GLD16(Wg[j] + k, &sW[(w * 32 + j * 8) * 64]);
        __syncthreads();
#pragma unroll
        for (int kk = 0; kk < 2; kk++) {
            const int sl = ((kk * 4 + qd + cl) & 7) * 8;
            s8v a[4], b[4];
#pragma unroll
            for (int mt = 0; mt < 4; mt++)
                a[mt] = *(const s8v*)&sA[(wm + mt * 16 + cl) * 64 + sl];
#pragma unroll
            for (int nt = 0; nt < 4; nt++)
                b[nt] = *(const s8v*)&sW[(wn + nt * 16 + cl) * 64 + sl];
#pragma unroll
            for (int mt = 0; mt < 4; mt++)
#pragma unroll
                for (int nt = 0; nt < 4; nt++)
                    acc[mt][nt] = __builtin_amdgcn_mfma_f32_16x16x32_bf16(
                        a[mt], b[nt], acc[mt][nt], 0, 0, 0);
        }
        __syncthreads();
    }

    float* Cf = (float*)Cv;
    if (EPI == 0) Cf += (size_t)blockIdx.z * M * ldc;
    short* Cs = (short*)Cv;
#pragma unroll
    for (int mt = 0; mt < 4; mt++) {
        const int row0 = bm + wm + mt * 16 + qd * 4;
#pragma unroll
        for (int nt = 0; nt < 4; nt++) {
            const int col = bn + wn + nt * 16 + cl;
            if (EPI == 3 && col >= XDBL_N) continue;
#pragma unroll
            for (int r = 0; r < 4; r++) {
                const float v = acc[mt][nt][r];
                if      (EPI == 2) Cs[(size_t)(row0 + r) * ldc + col] = (short)f2bf(v);
                else if (EPI == 3) atomicAdd(&Cf[(size_t)(row0 + r) * ldc + col], v);
                else               Cf[(size_t)(row0 + r) * ldc + col] = v;
            }
        }
    }
}

// named entry points (profiling visibility)
__global__ __launch_bounds__(256)
void k_gemm_inproj(const short* A, const short* W, short* C)
{ gemm_body<2>(A, D_MODEL, W, D_MODEL, C, D_IN2, BL, D_MODEL); }

__global__ __launch_bounds__(256)
void k_gemm_xproj(const short* A, const short* W, float* C)
{ gemm_body<3>(A, D_INNER, W, D_INNER, C, XDBL_N, BL, D_INNER / XPROJ_SPLITS); }

__global__ __launch_bounds__(256)
void k_gemm_outproj(const short* A, const short* W, float* C)
{ gemm_body<0>(A, D_INNER, W, D_INNER, C, D_MODEL, BL, D_INNER / OUT_SPLITS); }

// ---- out_proj split-K reduce: out = P0 + P1 (float4) ----
__global__ __launch_bounds__(256)
void k_reduce_out(const float* __restrict__ P, float* __restrict__ out)
{
    const int i = blockIdx.x * 256 + threadIdx.x;   // float4 index
    const float4 a = ((const float4*)P)[i];
    const float4 b = ((const float4*)(P + (size_t)BL * D_MODEL))[i];
    ((float4*)out)[i] = make_float4(a.x + b.x, a.y + b.y, a.z + b.z, a.w + b.w);
}

// ---- dt_proj: dt = softplus(xdbl_f[:, :128] @ dtw^T + bias), 1 barrier ----
__global__ __launch_bounds__(256)
void k_gemm_dt(const float* __restrict__ Af, const short* __restrict__ W,
               const float* __restrict__ bias, float* __restrict__ C)
{
    __shared__ short sA[2 * 128 * 64];
    __shared__ short sW[2 * 128 * 64];

    const int tid = threadIdx.x;
    const int w   = tid >> 6;
    const int L   = tid & 63;
    const int bm  = blockIdx.y * 128;
    const int bn  = blockIdx.x * 128;

#pragma unroll
    for (int ci = 0; ci < 8; ci++) {
        const int c_lin = tid * 8 + ci;
        const int r = c_lin >> 4;
        const int c = c_lin & 15;
        const float* src = Af + (size_t)(bm + r) * XDBL_N + c * 8;
        const float4 u = *(const float4*)src;
        const float4 v = *(const float4*)(src + 4);
        const int half = c >> 3, cc = c & 7;
        const int slot = (cc + r) & 7;
        uint4 o;
        o.x = packbf(u.x, u.y); o.y = packbf(u.z, u.w);
        o.z = packbf(v.x, v.y); o.w = packbf(v.z, v.w);
        *(uint4*)&sA[half * 8192 + r * 64 + slot * 8] = o;
    }
    const int rsub = L >> 3;
    const int c8   = (((L & 7) - rsub) & 7) * 8;
#pragma unroll
    for (int half = 0; half < 2; half++)
#pragma unroll
        for (int j = 0; j < 4; j++)
            GLD16(W + (size_t)(bn + w * 32 + j * 8 + rsub) * DT_RANK + half * 64 + c8,
                  &sW[half * 8192 + (w * 32 + j * 8) * 64]);
    __syncthreads();

    const int wm = (w >> 1) * 64;
    const int wn = (w & 1) * 64;
    const int cl = L & 15;
    const int qd = L >> 4;

    f4v acc[4][4];
#pragma unroll
    for (int i = 0; i < 4; i++)
#pragma unroll
        for (int j = 0; j < 4; j++) acc[i][j] = (f4v){0.f, 0.f, 0.f, 0.f};

#pragma unroll
    for (int ks = 0; ks < 4; ks++) {
        const int half = ks >> 1;
        const int sl = (((ks & 1) * 4 + qd + cl) & 7) * 8;
        s8v a[4], b[4];
#pragma unroll
        for (int mt = 0; mt < 4; mt++)
            a[mt] = *(const s8v*)&sA[half * 8192 + (wm + mt * 16 + cl) * 64 + sl];
#pragma unroll
        for (int nt = 0; nt < 4; nt++)
            b[nt] = *(const s8v*)&sW[half * 8192 + (wn + nt * 16 + cl) * 64 + sl];
#pragma unroll
        for (int mt = 0; mt < 4; mt++)
#pragma unroll
            for (int nt = 0; nt < 4; nt++)
                acc[mt][nt] = __builtin_amdgcn_mfma_f32_16x16x32_bf16(
                    a[mt], b[nt], acc[mt][nt], 0, 0, 0);
    }

#pragma unroll
    for (int mt = 0; mt < 4; mt++) {
        const int row0 = bm + wm + mt * 16 + qd * 4;
#pragma unroll
        for (int nt = 0; nt < 4; nt++) {
            const int col = bn + wn + nt * 16 + cl;
            const float bc = bias[col];
#pragma unroll
            for (int r = 0; r < 4; r++)
                C[(size_t)(row0 + r) * D_INNER + col] = softplus_f(acc[mt][nt][r] + bc);
        }
    }
}

// ---- causal depthwise conv1d (K=4) + SiLU ----
__global__ __launch_bounds__(256)
void k_conv(const short* __restrict__ xz_bf, const float* __restrict__ cw,
            const float* __restrict__ cb, short* __restrict__ x_bf)
{
    const int idx = blockIdx.x * 256 + threadIdx.x;
    const int d  = idx & (D_INNER - 1);
    const int bl = idx >> 12;
    const int l  = bl & (SEQLEN - 1);
    const int b  = bl >> 10;
    const short* xb = xz_bf + (size_t)b * SEQLEN * D_IN2 + d;
    float acc = cb[d];
#pragma unroll
    for (int k = 0; k < D_CONVK; k++) {
        const int ll = l + k - (D_CONVK - 1);
        if (ll >= 0) acc = fmaf(bf2f(xb[(size_t)ll * D_IN2]), cw[d * D_CONVK + k], acc);
    }
    x_bf[idx] = (short)f2bf(silu_f(acc));
}

// ================= chunked selective scan =================
__global__ __launch_bounds__(256)
void k_scan_p1(const short* __restrict__ x_bf, const float* __restrict__ dt,
               const float* __restrict__ xdbl, const float* __restrict__ A_log,
               float* __restrict__ h_end, float* __restrict__ Pprod)
{
    const int c   = blockIdx.y;
    const int ch0 = blockIdx.x * 64;
    const int b   = ch0 >> 12;
    const int d0  = ch0 & (D_INNER - 1);
    const int tid = threadIdx.x;
    const int g   = tid >> 2;
    const int q   = tid & 3;
    const int d   = d0 + g;

    const float4 Al = *(const float4*)&A_log[(d << 4) + (q << 2)];
    float An[4] = {-__expf(Al.x), -__expf(Al.y), -__expf(Al.z), -__expf(Al.w)};
    float h[4]  = {0.f, 0.f, 0.f, 0.f};
    float Pp[4] = {1.f, 1.f, 1.f, 1.f};

    __shared__ float s_x [16][68];
    __shared__ float s_dt[16][68];
    __shared__ float s_B [16][20];

    const int lt  = tid >> 4;
    const int ld4 = (tid & 15) * 4;

    for (int sub = 0; sub < LCHUNK / 16; sub++) {
        const int l0 = c * LCHUNK + sub * 16;
        const size_t bl = (size_t)(b * SEQLEN + l0 + lt);
        __syncthreads();
        {
            const short4 sx = *(const short4*)&x_bf[bl * D_INNER + d0 + ld4];
            const float4 dv = *(const float4*)&dt[bl * D_INNER + d0 + ld4];
            *(float4*)&s_x [lt][ld4] =
                make_float4(bf2f(sx.x), bf2f(sx.y), bf2f(sx.z), bf2f(sx.w));
            *(float4*)&s_dt[lt][ld4] = dv;
            if (tid < 64) {
                const int t2 = tid >> 2, k = (tid & 3) * 4;
                const size_t bl2 = (size_t)(b * SEQLEN + l0 + t2);
                *(float4*)&s_B[t2][k] =
                    *(const float4*)&xdbl[bl2 * XDBL_N + DT_RANK + k];
            }
        }
        __syncthreads();
#pragma unroll
        for (int t = 0; t < 16; t++) {
            const float xv  = s_x [t][g];
            const float dtv = s_dt[t][g];
            const float4 Bq = *(const float4*)&s_B[t][q * 4];
            const float Bv[4] = {Bq.x, Bq.y, Bq.z, Bq.w};
            const float dtx = dtv * xv;
#pragma unroll
            for (int j = 0; j < 4; j++) {
                const float dA = __expf(dtv * An[j]);
                h[j]  = fmaf(h[j], dA, dtx * Bv[j]);
                Pp[j] *= dA;
            }
        }
    }
    const size_t i0 = (size_t)c * CHW + (((size_t)(b * D_INNER + d)) << 4) + (q << 2);
    *(float4*)&h_end[i0] = make_float4(h[0], h[1], h[2], h[3]);
    *(float4*)&Pprod[i0] = make_float4(Pp[0], Pp[1], Pp[2], Pp[3]);
}

__global__ __launch_bounds__(256)
void k_scan_p3(const short* __restrict__ x_bf, short* __restrict__ y_bf,
               const float* __restrict__ dt, const float* __restrict__ xdbl,
               const short* __restrict__ xz_bf, const float* __restrict__ A_log,
               const float* __restrict__ Dvec,
               const float* __restrict__ h_end, const float* __restrict__ Pbuf)
{
    const int c   = blockIdx.y;
    const int ch0 = blockIdx.x * 64;
    const int b   = ch0 >> 12;
    const int d0  = ch0 & (D_INNER - 1);
    const int tid = threadIdx.x;
    const int g   = tid >> 2;
    const int q   = tid & 3;
    const int d   = d0 + g;

    const float4 Al = *(const float4*)&A_log[(d << 4) + (q << 2)];
    float An[4] = {-__expf(Al.x), -__expf(Al.y), -__expf(Al.z), -__expf(Al.w)};
    const float Dd = Dvec[d];

    float h[4] = {0.f, 0.f, 0.f, 0.f};
    const size_t base = (((size_t)(b * D_INNER + d)) << 4) + (q << 2);
    for (int j = 0; j < c; j++) {
        const float4 he = *(const float4*)&h_end[(size_t)j * CHW + base];
        const float4 Pp = *(const float4*)&Pbuf [(size_t)j * CHW + base];
        h[0] = fmaf(Pp.x, h[0], he.x);
        h[1] = fmaf(Pp.y, h[1], he.y);
        h[2] = fmaf(Pp.z, h[2], he.z);
        h[3] = fmaf(Pp.w, h[3], he.w);
    }

    __shared__ float s_x [16][68];
    __shared__ float s_dt[16][68];
    __shared__ float s_z [16][68];
    __shared__ float s_B [16][20];
    __shared__ float s_C [16][20];

    const int lt  = tid >> 4;
    const int ld4 = (tid & 15) * 4;

    for (int sub = 0; sub < LCHUNK / 16; sub++) {
        const int l0 = c * LCHUNK + sub * 16;
        const size_t bl = (size_t)(b * SEQLEN + l0 + lt);
        __syncthreads();
        {
            const short4 sx = *(const short4*)&x_bf[bl * D_INNER + d0 + ld4];
            const float4 dv = *(const float4*)&dt[bl * D_INNER + d0 + ld4];
            const short4 zv = *(const short4*)&xz_bf[bl * D_IN2 + D_INNER + d0 + ld4];
            *(float4*)&s_x [lt][ld4] =
                make_float4(bf2f(sx.x), bf2f(sx.y), bf2f(sx.z), bf2f(sx.w));
            *(float4*)&s_dt[lt][ld4] = dv;
            *(float4*)&s_z [lt][ld4] =
                make_float4(bf2f(zv.x), bf2f(zv.y), bf2f(zv.z), bf2f(zv.w));
            if (tid < 128) {
                const int t2 = (tid & 63) >> 2, k = (tid & 3) * 4;
                const size_t bl2 = (size_t)(b * SEQLEN + l0 + t2);
                const int off = (tid < 64) ? 0 : D_STATE;
                const float4 v =
                    *(const float4*)&xdbl[bl2 * XDBL_N + DT_RANK + off + k];
                if (tid < 64) *(float4*)&s_B[t2][k] = v;
                else          *(float4*)&s_C[t2][k] = v;
            }
        }
        __syncthreads();
        const size_t orow = (size_t)(b * SEQLEN + l0);
#pragma unroll
        for (int t = 0; t < 16; t++) {
            const float xv  = s_x [t][g];
            const float dtv = s_dt[t][g];
            const float4 Bq = *(const float4*)&s_B[t][q * 4];
            const float4 Cq = *(const float4*)&s_C[t][q * 4];
            const float Bv[4] = {Bq.x, Bq.y, Bq.z, Bq.w};
            const float Cv[4] = {Cq.x, Cq.y, Cq.z, Cq.w};
            const float dtx = dtv * xv;
            float p = 0.f;
#pragma unroll
            for (int j = 0; j < 4; j++) {
                const float dA = __expf(dtv * An[j]);
                h[j] = fmaf(h[j], dA, dtx * Bv[j]);
                p = fmaf(h[j], Cv[j], p);
            }
            p = quad_sum(p);
            if (q == 0) {
                const float yv = fmaf(xv, Dd, p) * silu_f(s_z[t][g]);
                y_bf[(orow + t) * D_INNER + d] = (short)f2bf(yv);
            }
        }
    }
}

extern "C" void kernel_launch(void* const* d_in, const int* in_sizes, int n_in,
                              void* d_out, int out_size, void* d_ws, size_t ws_size,
                              hipStream_t stream)
{
    const float* hidden     = (const float*)d_in[0];
    const float* in_proj_w  = (const float*)d_in[1];
    const float* conv_w     = (const float*)d_in[2];
    const float* conv_b     = (const float*)d_in[3];
    const float* x_proj_w   = (const float*)d_in[4];
    const float* dt_proj_w  = (const float*)d_in[5];
    const float* dt_proj_b  = (const float*)d_in[6];
    const float* A_log      = (const float*)d_in[7];
    const float* Dvec       = (const float*)d_in[8];
    const float* out_proj_w = (const float*)d_in[9];
    float* out = (float*)d_out;

    // ---- workspace layout (stream-ordered aliasing, ~140.3 MB) ----
    const size_t MB = 1ull << 20;
    char* ws = (char*)d_ws;
    short* xz_bf   = (short*)(ws);                  // [0,32)   bf16 [BL,8192]
    short* x_bf    = (short*)(ws + 32 * MB);        // [32,48)  bf16 [BL,4096]
    short* ipw_bf  = (short*)(ws + 48 * MB);        // [48,80)  dead after in_proj
    short* y_bf    = (short*)(ws + 48 * MB);        // [48,64)  alias (phase3)
    float* h_end   = (float*)(ws + 64 * MB);        // [64,72)  alias (phase1)
    float* Pbuf    = (float*)(ws + 72 * MB);        // [72,80)  alias (phase1)
    short* hid_bf  = (short*)(ws + 80 * MB);        // [80,88)  dead after in_proj
    short* opw_bf  = (short*)(ws + 88 * MB);        // [88,104)
    float* dt_f32  = (float*)(ws + 104 * MB);       // [104,136) dead after p3
    float* op_part = (float*)(ws + 104 * MB);       // alias: out_proj partials 2x16MB
    short* xpw_bf  = (short*)(ws + 136 * MB);       // [136,138)
    short* dtw_bf  = (short*)(ws + 138 * MB);       // [138,139)
    float* xdbl_f  = (float*)(ws + 139 * MB);       // 1.25 MB, atomic target

    const dim3 blk(256);

    // 0) fused casts + zero-fills
    k_cast_all<<<dim3(NB_HID + NB_IPW + NB_XPW + NB_XPWZ + NB_DTW + NB_OPW + NB_XDBLZ),
                blk, 0, stream>>>(
        hidden, (uint32_t*)hid_bf, in_proj_w, (uint32_t*)ipw_bf,
        x_proj_w, (uint32_t*)xpw_bf, dt_proj_w, (uint32_t*)dtw_bf,
        out_proj_w, (uint32_t*)opw_bf,
        (uint32_t*)(xpw_bf + (size_t)XDBL_N * D_INNER),
        (uint32_t*)xdbl_f);

    // 1) in_proj -> xz_bf (bf16 epilogue)
    k_gemm_inproj<<<dim3(D_IN2 / 128, BL / 128, 1), blk, 0, stream>>>(
        hid_bf, ipw_bf, xz_bf);

    // 2) conv + SiLU -> x_bf
    k_conv<<<dim3((BL * D_INNER) / 256), blk, 0, stream>>>(
        xz_bf, conv_w, conv_b, x_bf);

    // 3) x_proj split-K=8: atomicAdd into xdbl_f
    k_gemm_xproj<<<dim3(XPW_NPAD / 128, BL / 128, XPROJ_SPLITS), blk, 0, stream>>>(
        x_bf, xpw_bf, xdbl_f);

    // 4) dt_proj + bias + softplus
    k_gemm_dt<<<dim3(D_INNER / 128, BL / 128), blk, 0, stream>>>(
        xdbl_f, dtw_bf, dt_proj_b, dt_f32);

    // 5) chunked selective scan
    k_scan_p1<<<dim3(BATCH * D_INNER / 64, NCHUNK - 1), blk, 0, stream>>>(
        x_bf, dt_f32, xdbl_f, A_log, h_end, Pbuf);
    k_scan_p3<<<dim3(BATCH * D_INNER / 64, NCHUNK), blk, 0, stream>>>(
        x_bf, y_bf, dt_f32, xdbl_f, xz_bf, A_log, Dvec, h_end, Pbuf);

    // 6) out_proj split-K=2 -> partials, then reduce into d_out
    k_gemm_outproj<<<dim3(D_MODEL / 128, BL / 128, OUT_SPLITS), blk, 0, stream>>>(
        y_bf, opw_bf, op_part);
    k_reduce_out<<<dim3(BL * D_MODEL / 4 / 256), blk, 0, stream>>>(op_part, out);
}